// Round 1
// baseline (335.571 us; speedup 1.0000x reference)
//
#include <hip/hip_runtime.h>

// ConstrainedSparsemax: per row solve sum(clip(z - tau, 0, u)) == 1.
// One block per row; entire row (z,u) held in registers (8x float4 each,
// 32 elements/thread). Bisection (36 iters) + 2 exact KKT refinements.

#define NCOLS   8192
#define THREADS 256
#define CHUNKS  8     // float4 chunks per thread: 8192/4/256
#define ITERS   36

__device__ __forceinline__ float wsum(float v) {
#pragma unroll
  for (int o = 32; o > 0; o >>= 1) v += __shfl_xor(v, o, 64);
  return v;
}
__device__ __forceinline__ float wmin(float v) {
#pragma unroll
  for (int o = 32; o > 0; o >>= 1) v = fminf(v, __shfl_xor(v, o, 64));
  return v;
}
__device__ __forceinline__ float wmax(float v) {
#pragma unroll
  for (int o = 32; o > 0; o >>= 1) v = fmaxf(v, __shfl_xor(v, o, 64));
  return v;
}

__global__ __launch_bounds__(THREADS, 4) void csparsemax_kernel(
    const float* __restrict__ zg, const float* __restrict__ ug,
    float* __restrict__ og) {
  const int row  = blockIdx.x;
  const int tid  = threadIdx.x;
  const int wave = tid >> 6;
  const int lane = tid & 63;

  const float4* zp = (const float4*)(zg + (size_t)row * NCOLS);
  const float4* up = (const float4*)(ug + (size_t)row * NCOLS);
  float4*       op = (float4*)(og + (size_t)row * NCOLS);

  float4 z[CHUNKS], u[CHUNKS];
#pragma unroll
  for (int j = 0; j < CHUNKS; ++j) {
    z[j] = zp[tid + j * THREADS];
    u[j] = up[tid + j * THREADS];
  }

  __shared__ float lsum[2][4];   // double-buffered cross-wave sums
  __shared__ float lmm[8];       // min/max slots
  __shared__ float l3[4][3];     // refinement: [wave][{cnt,sz,su}]

  // ---- initial bisection bounds: lo = min(z-u), hi = max(z) ----
  float lmin = 3.4e38f, lmax = -3.4e38f;
#pragma unroll
  for (int j = 0; j < CHUNKS; ++j) {
    lmin = fminf(lmin, fminf(fminf(z[j].x - u[j].x, z[j].y - u[j].y),
                             fminf(z[j].z - u[j].z, z[j].w - u[j].w)));
    lmax = fmaxf(lmax, fmaxf(fmaxf(z[j].x, z[j].y), fmaxf(z[j].z, z[j].w)));
  }
  lmin = wmin(lmin);
  lmax = wmax(lmax);
  if (lane == 0) { lmm[wave] = lmin; lmm[4 + wave] = lmax; }
  __syncthreads();
  float lo = fminf(fminf(lmm[0], lmm[1]), fminf(lmm[2], lmm[3]));
  float hi = fmaxf(fmaxf(lmm[4], lmm[5]), fmaxf(lmm[6], lmm[7]));

  // ---- bisection: one barrier per iteration (double-buffered LDS) ----
#pragma unroll 1
  for (int it = 0; it < ITERS; ++it) {
    float mid = 0.5f * (lo + hi);
    float s0 = 0.f, s1 = 0.f, s2 = 0.f, s3 = 0.f;
#pragma unroll
    for (int j = 0; j < CHUNKS; ++j) {
      s0 += __builtin_amdgcn_fmed3f(z[j].x - mid, 0.f, u[j].x);
      s1 += __builtin_amdgcn_fmed3f(z[j].y - mid, 0.f, u[j].y);
      s2 += __builtin_amdgcn_fmed3f(z[j].z - mid, 0.f, u[j].z);
      s3 += __builtin_amdgcn_fmed3f(z[j].w - mid, 0.f, u[j].w);
    }
    float s = wsum((s0 + s1) + (s2 + s3));
    if (lane == 0) lsum[it & 1][wave] = s;
    __syncthreads();
    float f = (lsum[it & 1][0] + lsum[it & 1][1]) +
              (lsum[it & 1][2] + lsum[it & 1][3]);
    if (f > 1.0f) lo = mid; else hi = mid;
  }

  float tau = 0.5f * (lo + hi);

  // ---- two rounds of exact KKT (Newton) refinement ----
#pragma unroll 1
  for (int r = 0; r < 2; ++r) {
    float cnt = 0.f, sz = 0.f, su = 0.f;
#pragma unroll
    for (int j = 0; j < CHUNKS; ++j) {
#define REFINE(c)                                          \
      {                                                    \
        float d  = z[j].c - tau;                           \
        bool  b1 = (d > 0.f) & (d < u[j].c);               \
        bool  b2 = d >= u[j].c;                            \
        cnt += b1 ? 1.f : 0.f;                             \
        sz  += b1 ? z[j].c : 0.f;                          \
        su  += b2 ? u[j].c : 0.f;                          \
      }
      REFINE(x) REFINE(y) REFINE(z) REFINE(w)
#undef REFINE
    }
    cnt = wsum(cnt); sz = wsum(sz); su = wsum(su);
    __syncthreads();   // prior round's l3 reads (and lsum reads) complete
    if (lane == 0) { l3[wave][0] = cnt; l3[wave][1] = sz; l3[wave][2] = su; }
    __syncthreads();
    float nA = l3[0][0] + l3[1][0] + l3[2][0] + l3[3][0];
    float SZ = l3[0][1] + l3[1][1] + l3[2][1] + l3[3][1];
    float SU = l3[0][2] + l3[1][2] + l3[2][2] + l3[3][2];
    float nt = (SZ + SU - 1.0f) / fmaxf(nA, 1.0f);
    tau = (nA > 0.f) ? nt : tau;
  }

  // ---- epilogue: probs = clip(z - tau, 0, u) ----
#pragma unroll
  for (int j = 0; j < CHUNKS; ++j) {
    float4 o;
    o.x = __builtin_amdgcn_fmed3f(z[j].x - tau, 0.f, u[j].x);
    o.y = __builtin_amdgcn_fmed3f(z[j].y - tau, 0.f, u[j].y);
    o.z = __builtin_amdgcn_fmed3f(z[j].z - tau, 0.f, u[j].z);
    o.w = __builtin_amdgcn_fmed3f(z[j].w - tau, 0.f, u[j].w);
    op[tid + j * THREADS] = o;
  }
}

extern "C" void kernel_launch(void* const* d_in, const int* in_sizes, int n_in,
                              void* d_out, int out_size, void* d_ws, size_t ws_size,
                              hipStream_t stream) {
  const float* z = (const float*)d_in[0];
  const float* u = (const float*)d_in[1];
  float*     out = (float*)d_out;
  const int rows = out_size / NCOLS;  // 4096
  csparsemax_kernel<<<rows, THREADS, 0, stream>>>(z, u, out);
}

// Round 3
// 322.250 us; speedup vs baseline: 1.0413x; 1.0413x over previous
//
#include <hip/hip_runtime.h>

// ConstrainedSparsemax: per row solve sum(clip(z - tau, 0, u)) == 1.
// One block per row. z,u pinned in registers (asm) so bisection never
// re-reads memory. 8 full-data bisection iters -> bracket ~0.034 wide ->
// compact undetermined elements (~tens) to LDS -> wave 0 finishes 30
// bisection iters + 2 exact KKT refinements on the tiny set. Overflow
// (cnt > CAP) falls back to full-data iterations (block-uniform branch).

#define NCOLS   8192
#define THREADS 256
#define CHUNKS  8     // float4 chunks per thread: 8192/4/256
#define K1      8     // full-data bisection iterations
#define TAILI   30    // compacted-set bisection iterations
#define CAP     1024  // LDS compaction capacity (elements)

__device__ __forceinline__ float wsum(float v) {
#pragma unroll
  for (int o = 32; o > 0; o >>= 1) v += __shfl_xor(v, o, 64);
  return v;
}
__device__ __forceinline__ float wmin(float v) {
#pragma unroll
  for (int o = 32; o > 0; o >>= 1) v = fminf(v, __shfl_xor(v, o, 64));
  return v;
}
__device__ __forceinline__ float wmax(float v) {
#pragma unroll
  for (int o = 32; o > 0; o >>= 1) v = fmaxf(v, __shfl_xor(v, o, 64));
  return v;
}

__global__ __launch_bounds__(THREADS, 4) void csparsemax_kernel(
    const float* __restrict__ zg, const float* __restrict__ ug,
    float* __restrict__ og) {
  const int row  = blockIdx.x;
  const int tid  = threadIdx.x;
  const int wave = tid >> 6;
  const int lane = tid & 63;

  const float4* zp = (const float4*)(zg + (size_t)row * NCOLS);
  const float4* up = (const float4*)(ug + (size_t)row * NCOLS);
  float4*       op = (float4*)(og + (size_t)row * NCOLS);

  __shared__ float lsum[2][4];   // double-buffered cross-wave sums
  __shared__ float lmm[8];       // min/max slots (reused for su partials)
  __shared__ float l3[4][3];     // overflow-path refinement
  __shared__ float za[CAP], ua[CAP];
  __shared__ int   scnt;
  __shared__ float stau;

  if (tid == 0) scnt = 0;

  float4 z[CHUNKS], u[CHUNKS];
#pragma unroll
  for (int j = 0; j < CHUNKS; ++j) {
    z[j] = zp[tid + j * THREADS];
    u[j] = up[tid + j * THREADS];
  }
  // Pin in registers: outputs of asm cannot be rematerialized from memory.
#pragma unroll
  for (int j = 0; j < CHUNKS; ++j) {
    asm volatile("" : "+v"(z[j].x), "+v"(z[j].y), "+v"(z[j].z), "+v"(z[j].w),
                      "+v"(u[j].x), "+v"(u[j].y), "+v"(u[j].z), "+v"(u[j].w));
  }

  // ---- initial bounds: lo = min(z-u), hi = max(z) ----
  float lmin = 3.4e38f, lmax = -3.4e38f;
#pragma unroll
  for (int j = 0; j < CHUNKS; ++j) {
    lmin = fminf(lmin, fminf(fminf(z[j].x - u[j].x, z[j].y - u[j].y),
                             fminf(z[j].z - u[j].z, z[j].w - u[j].w)));
    lmax = fmaxf(lmax, fmaxf(fmaxf(z[j].x, z[j].y), fmaxf(z[j].z, z[j].w)));
  }
  lmin = wmin(lmin);
  lmax = wmax(lmax);
  if (lane == 0) { lmm[wave] = lmin; lmm[4 + wave] = lmax; }
  __syncthreads();   // B1 (also orders scnt init)
  float lo = fminf(fminf(lmm[0], lmm[1]), fminf(lmm[2], lmm[3]));
  float hi = fmaxf(fmaxf(lmm[4], lmm[5]), fmaxf(lmm[6], lmm[7]));

  // ---- K1 full-data bisection iterations (register-resident data) ----
#pragma unroll 1
  for (int it = 0; it < K1; ++it) {
    float mid = 0.5f * (lo + hi);
    float s0 = 0.f, s1 = 0.f, s2 = 0.f, s3 = 0.f;
#pragma unroll
    for (int j = 0; j < CHUNKS; ++j) {
      s0 += __builtin_amdgcn_fmed3f(z[j].x - mid, 0.f, u[j].x);
      s1 += __builtin_amdgcn_fmed3f(z[j].y - mid, 0.f, u[j].y);
      s2 += __builtin_amdgcn_fmed3f(z[j].z - mid, 0.f, u[j].z);
      s3 += __builtin_amdgcn_fmed3f(z[j].w - mid, 0.f, u[j].w);
    }
    float s = wsum((s0 + s1) + (s2 + s3));
    if (lane == 0) lsum[it & 1][wave] = s;
    __syncthreads();
    float f = (lsum[it & 1][0] + lsum[it & 1][1]) +
              (lsum[it & 1][2] + lsum[it & 1][3]);
    if (f > 1.0f) lo = mid; else hi = mid;
  }

  // ---- classification + compaction against bracket [lo, hi] ----
  // z <= lo           -> contributes 0 for any tau in bracket
  // z - u >= hi       -> contributes exactly u  (su_base)
  // otherwise         -> undetermined, push to LDS
  const float lo_c = lo, hi_c = hi;
  float su = 0.f;
#pragma unroll
  for (int j = 0; j < CHUNKS; ++j) {
#define CLASSIFY(c)                                          \
    {                                                        \
      float zz = z[j].c, uu = u[j].c;                        \
      float d  = zz - uu;                                    \
      bool  sat = d >= hi_c;                                 \
      bool  act = (zz > lo_c) && (d < hi_c);                 \
      su += sat ? uu : 0.f;                                  \
      if (act) {                                             \
        int k = atomicAdd(&scnt, 1);                         \
        if (k < CAP) { za[k] = zz; ua[k] = uu; }             \
      }                                                      \
    }
    CLASSIFY(x) CLASSIFY(y) CLASSIFY(z) CLASSIFY(w)
#undef CLASSIFY
  }
  su = wsum(su);
  if (lane == 0) lmm[wave] = su;
  __syncthreads();   // Bc: orders za/ua/scnt writes + su partials
  const float su_base = (lmm[0] + lmm[1]) + (lmm[2] + lmm[3]);
  const int cnt = scnt;

  float tau;
  if (cnt <= CAP) {
    // ---- wave 0 finishes alone on the compacted set (no barriers) ----
    if (wave == 0) {
      float tlo = lo, thi = hi;
#pragma unroll 1
      for (int it = 0; it < TAILI; ++it) {
        float mid = 0.5f * (tlo + thi);
        float p = 0.f;
        for (int k = lane; k < cnt; k += 64)
          p += __builtin_amdgcn_fmed3f(za[k] - mid, 0.f, ua[k]);
        float f = su_base + wsum(p);
        if (f > 1.0f) tlo = mid; else thi = mid;
      }
      float t = 0.5f * (tlo + thi);
      // two exact KKT refinements on the compacted set
#pragma unroll 1
      for (int r = 0; r < 2; ++r) {
        float c = 0.f, sz = 0.f, s2 = 0.f;
        for (int k = lane; k < cnt; k += 64) {
          float d  = za[k] - t;
          bool  b1 = (d > 0.f) & (d < ua[k]);
          bool  b2 = d >= ua[k];
          c  += b1 ? 1.f : 0.f;
          sz += b1 ? za[k] : 0.f;
          s2 += b2 ? ua[k] : 0.f;
        }
        c  = wsum(c);
        sz = wsum(sz);
        s2 = wsum(s2) + su_base;
        float nt = (sz + s2 - 1.0f) / fmaxf(c, 1.0f);
        t = (c > 0.f) ? nt : t;
      }
      if (lane == 0) stau = t;
    }
    __syncthreads();   // Bf: publish tau
    tau = stau;
  } else {
    // ---- overflow fallback: continue full-data (block-uniform branch) ----
#pragma unroll 1
    for (int it = K1; it < K1 + TAILI; ++it) {
      float mid = 0.5f * (lo + hi);
      float s0 = 0.f, s1 = 0.f, s2 = 0.f, s3 = 0.f;
#pragma unroll
      for (int j = 0; j < CHUNKS; ++j) {
        s0 += __builtin_amdgcn_fmed3f(z[j].x - mid, 0.f, u[j].x);
        s1 += __builtin_amdgcn_fmed3f(z[j].y - mid, 0.f, u[j].y);
        s2 += __builtin_amdgcn_fmed3f(z[j].z - mid, 0.f, u[j].z);
        s3 += __builtin_amdgcn_fmed3f(z[j].w - mid, 0.f, u[j].w);
      }
      float s = wsum((s0 + s1) + (s2 + s3));
      if (lane == 0) lsum[it & 1][wave] = s;
      __syncthreads();
      float f = (lsum[it & 1][0] + lsum[it & 1][1]) +
                (lsum[it & 1][2] + lsum[it & 1][3]);
      if (f > 1.0f) lo = mid; else hi = mid;
    }
    tau = 0.5f * (lo + hi);
#pragma unroll 1
    for (int r = 0; r < 2; ++r) {
      float cnt2 = 0.f, sz = 0.f, su2 = 0.f;
#pragma unroll
      for (int j = 0; j < CHUNKS; ++j) {
#define REFINE(c)                                          \
        {                                                  \
          float d  = z[j].c - tau;                         \
          bool  b1 = (d > 0.f) & (d < u[j].c);             \
          bool  b2 = d >= u[j].c;                          \
          cnt2 += b1 ? 1.f : 0.f;                          \
          sz   += b1 ? z[j].c : 0.f;                       \
          su2  += b2 ? u[j].c : 0.f;                       \
        }
        REFINE(x) REFINE(y) REFINE(z) REFINE(w)
#undef REFINE
      }
      cnt2 = wsum(cnt2); sz = wsum(sz); su2 = wsum(su2);
      __syncthreads();
      if (lane == 0) { l3[wave][0] = cnt2; l3[wave][1] = sz; l3[wave][2] = su2; }
      __syncthreads();
      float nA = l3[0][0] + l3[1][0] + l3[2][0] + l3[3][0];
      float SZ = l3[0][1] + l3[1][1] + l3[2][1] + l3[3][1];
      float SU = l3[0][2] + l3[1][2] + l3[2][2] + l3[3][2];
      float nt = (SZ + SU - 1.0f) / fmaxf(nA, 1.0f);
      tau = (nA > 0.f) ? nt : tau;
    }
  }

  // ---- epilogue: probs = clip(z - tau, 0, u) ----
#pragma unroll
  for (int j = 0; j < CHUNKS; ++j) {
    float4 o;
    o.x = __builtin_amdgcn_fmed3f(z[j].x - tau, 0.f, u[j].x);
    o.y = __builtin_amdgcn_fmed3f(z[j].y - tau, 0.f, u[j].y);
    o.z = __builtin_amdgcn_fmed3f(z[j].z - tau, 0.f, u[j].z);
    o.w = __builtin_amdgcn_fmed3f(z[j].w - tau, 0.f, u[j].w);
    op[tid + j * THREADS] = o;
  }
}

extern "C" void kernel_launch(void* const* d_in, const int* in_sizes, int n_in,
                              void* d_out, int out_size, void* d_ws, size_t ws_size,
                              hipStream_t stream) {
  const float* z = (const float*)d_in[0];
  const float* u = (const float*)d_in[1];
  float*     out = (float*)d_out;
  const int rows = out_size / NCOLS;  // 4096
  csparsemax_kernel<<<rows, THREADS, 0, stream>>>(z, u, out);
}